// Round 2
// baseline (5815.682 us; speedup 1.0000x reference)
//
#include <hip/hip_runtime.h>
#include <hip/hip_bf16.h>

#define D 128
#define N_TAXON 100000
#define N_SOTU 200000
#define E_HP 200000
#define E_RH 2000000
#define OUTC 64

typedef __hip_bfloat16 bf16;

__device__ __forceinline__ float bflo(unsigned u) { return __uint_as_float(u << 16); }
__device__ __forceinline__ float bfhi(unsigned u) { return __uint_as_float(u & 0xffff0000u); }

__device__ __forceinline__ unsigned short f2bf(float x) {
    unsigned u = __float_as_uint(x);
    unsigned r = (u + 0x7fffu + ((u >> 16) & 1u)) >> 16;   // round-to-nearest-even
    return (unsigned short)r;
}
__device__ __forceinline__ unsigned packbf(float a, float b) {
    return (unsigned)f2bf(a) | ((unsigned)f2bf(b) << 16);
}

// ---------------- count per-dst degree ----------------
__global__ __launch_bounds__(256) void count_kernel(const int* __restrict__ hp_dst,
                                                    const int* __restrict__ rh_dst,
                                                    unsigned* cnt_t, unsigned* cnt_s)
{
    int stride = gridDim.x * blockDim.x;
    for (int i = blockIdx.x * blockDim.x + threadIdx.x; i < E_HP + E_RH; i += stride) {
        if (i < E_HP) atomicAdd(&cnt_t[hp_dst[i]], 1u);
        else          atomicAdd(&cnt_s[rh_dst[i - E_HP]], 1u);
    }
}

// ---------------- scatter-add: accum[dst] += src row ----------------
// one wave (64 lanes) per edge, 2 elements per lane; SRCBF: src rows are bf16
template<bool SRCBF>
__global__ __launch_bounds__(256) void scatter_kernel(const void* __restrict__ xsrc_,
                                                      const int* __restrict__ src,
                                                      const int* __restrict__ dst,
                                                      float* __restrict__ accum, long nwork)
{
    long stride = (long)gridDim.x * blockDim.x;
    for (long idx = (long)blockIdx.x * blockDim.x + threadIdx.x; idx < nwork; idx += stride) {
        int e = (int)(idx >> 6);
        int t = (int)(idx & 63);
        int s  = src[e];
        int d0 = dst[e];
        float a, b;
        if (SRCBF) {
            unsigned xp = ((const unsigned*)xsrc_)[(size_t)s * 64 + t];
            a = bflo(xp); b = bfhi(xp);
        } else {
            float2 x2 = ((const float2*)xsrc_)[(size_t)s * 64 + t];
            a = x2.x; b = x2.y;
        }
        float* ap = accum + (size_t)d0 * D + 2 * t;
        atomicAdd(ap,     a);
        atomicAdd(ap + 1, b);
    }
}

// ---------------- conv: out = relu(mean @ Wl + b + xdst @ Wr), bf16 out ----------------
// block = 256 threads = 4 waves, one row per wave; weights as packed bf16 pairs in LDS (64KB)
template<bool XBF>
__global__ __launch_bounds__(256) void conv_kernel(const float* __restrict__ sumbuf,
                                                   const unsigned* __restrict__ cnt,
                                                   const void* __restrict__ xdst_,
                                                   const float* __restrict__ Wl,
                                                   const float* __restrict__ Wr,
                                                   const float* __restrict__ bias,
                                                   bf16* __restrict__ out, int nrows)
{
    __shared__ unsigned sWl[D][D / 2];   // sWl[k][t] = bf16 pair (Wl[k][2t], Wl[k][2t+1])
    __shared__ unsigned sWr[D][D / 2];
    for (int i = threadIdx.x; i < D * D / 2; i += 256) {
        float2 wl = ((const float2*)Wl)[i];
        ((unsigned*)sWl)[i] = packbf(wl.x, wl.y);
        float2 wr = ((const float2*)Wr)[i];
        ((unsigned*)sWr)[i] = packbf(wr.x, wr.y);
    }
    __syncthreads();

    int wave = threadIdx.x >> 6;
    int lane = threadIdx.x & 63;
    float2 bias2 = ((const float2*)bias)[lane];

    for (int r = blockIdx.x * 4 + wave; r < nrows; r += gridDim.x * 4) {
        float2 s2 = ((const float2*)sumbuf)[(size_t)r * 64 + lane];
        unsigned c = cnt[r];
        float inv = 1.0f / (float)(c > 0u ? c : 1u);
        float m0 = s2.x * inv, m1 = s2.y * inv;
        float x0, x1;
        if (XBF) {
            unsigned xp = ((const unsigned*)xdst_)[(size_t)r * 64 + lane];
            x0 = bflo(xp); x1 = bfhi(xp);
        } else {
            float2 x2 = ((const float2*)xdst_)[(size_t)r * 64 + lane];
            x0 = x2.x; x1 = x2.y;
        }
        float acc0 = bias2.x, acc1 = bias2.y;
#pragma unroll 8
        for (int k2 = 0; k2 < 64; ++k2) {
            float ma = __shfl(m0, k2, 64);   // mean[2*k2]
            float mb = __shfl(m1, k2, 64);   // mean[2*k2+1]
            float xa = __shfl(x0, k2, 64);
            float xb = __shfl(x1, k2, 64);
            unsigned wl0 = sWl[2 * k2][lane];
            unsigned wl1 = sWl[2 * k2 + 1][lane];
            unsigned wr0 = sWr[2 * k2][lane];
            unsigned wr1 = sWr[2 * k2 + 1][lane];
            acc0 += ma * bflo(wl0) + mb * bflo(wl1) + xa * bflo(wr0) + xb * bflo(wr1);
            acc1 += ma * bfhi(wl0) + mb * bfhi(wl1) + xa * bfhi(wr0) + xb * bfhi(wr1);
        }
        ((unsigned*)out)[(size_t)r * 64 + lane] = packbf(fmaxf(acc0, 0.0f), fmaxf(acc1, 0.0f));
    }
}

// ---------------- final: out = h @ Wlin + blin (128 -> 64), f32 out ----------------
__global__ __launch_bounds__(256) void final_kernel(const bf16* __restrict__ h,
                                                    const float* __restrict__ W,
                                                    const float* __restrict__ b,
                                                    float* __restrict__ out, int nrows)
{
    __shared__ unsigned short sW[D * OUTC];   // bf16 bits, 16KB
    for (int i = threadIdx.x; i < D * OUTC; i += 256) sW[i] = f2bf(W[i]);
    __syncthreads();

    int wave = threadIdx.x >> 6;
    int lane = threadIdx.x & 63;
    float bc = b[lane];

    for (int r = blockIdx.x * 4 + wave; r < nrows; r += gridDim.x * 4) {
        unsigned hp = ((const unsigned*)h)[(size_t)r * 64 + lane];
        float h0 = bflo(hp), h1 = bfhi(hp);
        float acc = bc;
#pragma unroll 8
        for (int k2 = 0; k2 < 64; ++k2) {
            float a  = __shfl(h0, k2, 64);
            float bb = __shfl(h1, k2, 64);
            acc += a  * __uint_as_float((unsigned)sW[(2 * k2) * OUTC + lane] << 16);
            acc += bb * __uint_as_float((unsigned)sW[(2 * k2 + 1) * OUTC + lane] << 16);
        }
        out[(size_t)r * OUTC + lane] = acc;
    }
}

extern "C" void kernel_launch(void* const* d_in, const int* in_sizes, int n_in,
                              void* d_out, int out_size, void* d_ws, size_t ws_size,
                              hipStream_t stream)
{
    const float* x_taxon = (const float*)d_in[0];
    const float* x_sotu  = (const float*)d_in[1];
    const int* hp_src = (const int*)d_in[2];
    const int* hp_dst = (const int*)d_in[3];
    const int* rh_src = (const int*)d_in[4];
    const int* rh_dst = (const int*)d_in[5];
    const float* W1l = (const float*)d_in[6];
    const float* W1r = (const float*)d_in[7];
    const float* b1  = (const float*)d_in[8];
    const float* W2l = (const float*)d_in[9];
    const float* W2r = (const float*)d_in[10];
    const float* b2  = (const float*)d_in[11];
    const float* W3l = (const float*)d_in[12];
    const float* W3r = (const float*)d_in[13];
    const float* b3  = (const float*)d_in[14];
    const float* Wlin = (const float*)d_in[15];
    const float* blin = (const float*)d_in[16];
    float* out = (float*)d_out;

    // workspace layout (bytes), total 231,600,000:
    //   [0           , 102,400,000) sum_sotu  f32 [200000][128]
    //   [102,400,000 , 153,600,000) sum_taxon f32 [100000][128]  (reused as h2 bf16 after conv1)
    //   [153,600,000 , 154,000,000) cnt_taxon u32
    //   [154,000,000 , 154,800,000) cnt_sotu  u32
    //   [154,800,000 , 180,400,000) taxon_h   bf16 [100000][128]
    //   [180,400,000 , 231,600,000) sotu_h    bf16 [200000][128]
    char* ws = (char*)d_ws;
    float*    sum_sotu  = (float*)(ws);
    float*    sum_taxon = (float*)(ws + 102400000);
    unsigned* cnt_t     = (unsigned*)(ws + 153600000);
    unsigned* cnt_s     = (unsigned*)(ws + 154000000);
    bf16*     taxon_h   = (bf16*)(ws + 154800000);
    bf16*     sotu_h    = (bf16*)(ws + 180400000);
    bf16*     h2        = (bf16*)(ws + 102400000);  // overlays sum_taxon (free after conv1)

    // zero sums + counts
    hipMemsetAsync(ws, 0, 154800000, stream);

    count_kernel<<<2048, 256, 0, stream>>>(hp_dst, rh_dst, cnt_t, cnt_s);

    // conv1 scatter (taxon->taxon, f32 src) and conv2 scatter (taxon->sotu, f32 src)
    scatter_kernel<false><<<4096, 256, 0, stream>>>(x_taxon, hp_src, hp_dst, sum_taxon, (long)E_HP * 64);
    scatter_kernel<false><<<8192, 256, 0, stream>>>(x_taxon, rh_src, rh_dst, sum_sotu, (long)E_RH * 64);

    // conv1: taxon_h = relu(mean1 @ W1l + b1 + x_taxon @ W1r)
    conv_kernel<false><<<4096, 256, 0, stream>>>(sum_taxon, cnt_t, x_taxon, W1l, W1r, b1, taxon_h, N_TAXON);
    // conv2: sotu_h = relu(mean2 @ W2l + b2 + x_sotu @ W2r)
    conv_kernel<false><<<4096, 256, 0, stream>>>(sum_sotu, cnt_s, x_sotu, W2l, W2r, b2, sotu_h, N_SOTU);

    // conv3 scatter: re-zero sum_sotu then scatter taxon_h (bf16 src)
    hipMemsetAsync(sum_sotu, 0, 102400000, stream);
    scatter_kernel<true><<<8192, 256, 0, stream>>>(taxon_h, rh_src, rh_dst, sum_sotu, (long)E_RH * 64);

    // conv3: h2 = relu(mean3 @ W3l + b3 + sotu_h @ W3r)
    conv_kernel<true><<<4096, 256, 0, stream>>>(sum_sotu, cnt_s, sotu_h, W3l, W3r, b3, h2, N_SOTU);

    // final linear (f32 out)
    final_kernel<<<4096, 256, 0, stream>>>(h2, Wlin, blin, out, N_SOTU);
}

// Round 3
// 3674.890 us; speedup vs baseline: 1.5825x; 1.5825x over previous
//
#include <hip/hip_runtime.h>
#include <hip/hip_bf16.h>

#define D 128
#define N_TAXON 100000
#define N_SOTU 200000
#define E_HP 200000
#define E_RH 2000000
#define OUTC 64

typedef __hip_bfloat16 bf16;

__device__ __forceinline__ float bflo(unsigned u) { return __uint_as_float(u << 16); }
__device__ __forceinline__ float bfhi(unsigned u) { return __uint_as_float(u & 0xffff0000u); }

__device__ __forceinline__ unsigned short f2bf(float x) {
    unsigned u = __float_as_uint(x);
    unsigned r = (u + 0x7fffu + ((u >> 16) & 1u)) >> 16;   // round-to-nearest-even
    return (unsigned short)r;
}
__device__ __forceinline__ unsigned packbf(float a, float b) {
    return (unsigned)f2bf(a) | ((unsigned)f2bf(b) << 16);
}

// ---------------- count per-dst degree ----------------
__global__ __launch_bounds__(256) void count_kernel(const int* __restrict__ hp_dst,
                                                    const int* __restrict__ rh_dst,
                                                    unsigned* cnt_t, unsigned* cnt_s)
{
    int stride = gridDim.x * blockDim.x;
    for (int i = blockIdx.x * blockDim.x + threadIdx.x; i < E_HP + E_RH; i += stride) {
        if (i < E_HP) atomicAdd(&cnt_t[hp_dst[i]], 1u);
        else          atomicAdd(&cnt_s[rh_dst[i - E_HP]], 1u);
    }
}

// ---------------- 3-phase exclusive scan (n <= 256*1024) ----------------
__global__ __launch_bounds__(256) void scanA_kernel(const unsigned* __restrict__ cnt,
                                                    unsigned* __restrict__ bsum, int n)
{
    int lane = threadIdx.x & 63, wv = threadIdx.x >> 6;
    __shared__ unsigned ws[4];
    int i = blockIdx.x * 256 + threadIdx.x;
    unsigned v = (i < n) ? cnt[i] : 0u;
    for (int off = 1; off < 64; off <<= 1) v += __shfl_xor(v, off, 64);
    if (lane == 0) ws[wv] = v;
    __syncthreads();
    if (threadIdx.x == 0) bsum[blockIdx.x] = ws[0] + ws[1] + ws[2] + ws[3];
}

__global__ __launch_bounds__(1024) void scanB_kernel(unsigned* __restrict__ bsum, int nb,
                                                     unsigned* __restrict__ total_out)
{
    int lane = threadIdx.x & 63, wv = threadIdx.x >> 6;
    __shared__ unsigned wsum[16];
    int i = threadIdx.x;
    unsigned v = (i < nb) ? bsum[i] : 0u;
    unsigned s = v;
    for (int off = 1; off < 64; off <<= 1) {
        unsigned t = __shfl_up(s, off, 64);
        if (lane >= off) s += t;
    }
    if (lane == 63) wsum[wv] = s;
    __syncthreads();
    unsigned woff = 0, tot = 0;
    for (int w = 0; w < 16; ++w) { if (w < wv) woff += wsum[w]; tot += wsum[w]; }
    if (i < nb) bsum[i] = woff + s - v;    // exclusive
    if (threadIdx.x == 0) *total_out = tot;
}

__global__ __launch_bounds__(256) void scanC_kernel(const unsigned* __restrict__ cnt,
                                                    const unsigned* __restrict__ bsum,
                                                    unsigned* __restrict__ row_ptr, int n)
{
    int lane = threadIdx.x & 63, wv = threadIdx.x >> 6;
    __shared__ unsigned wsum[4];
    int i = blockIdx.x * 256 + threadIdx.x;
    unsigned v = (i < n) ? cnt[i] : 0u;
    unsigned s = v;
    for (int off = 1; off < 64; off <<= 1) {
        unsigned t = __shfl_up(s, off, 64);
        if (lane >= off) s += t;
    }
    if (lane == 63) wsum[wv] = s;
    __syncthreads();
    unsigned woff = bsum[blockIdx.x];
    for (int w = 0; w < wv; ++w) woff += wsum[w];
    if (i < n) row_ptr[i] = woff + s - v;
}

// ---------------- fill CSR neighbor lists via atomic cursor ----------------
__global__ __launch_bounds__(256) void fill_kernel(const int* __restrict__ src,
                                                   const int* __restrict__ dst,
                                                   unsigned* __restrict__ cursor,
                                                   int* __restrict__ sorted, int n)
{
    int stride = gridDim.x * blockDim.x;
    for (int i = blockIdx.x * blockDim.x + threadIdx.x; i < n; i += stride) {
        unsigned pos = atomicAdd(&cursor[dst[i]], 1u);
        sorted[pos] = src[i];
    }
}

// ---------------- cast f32 rows -> packed bf16 pairs ----------------
__global__ __launch_bounds__(256) void cast_kernel(const float* __restrict__ x,
                                                   unsigned* __restrict__ xb, int npairs)
{
    int stride = gridDim.x * blockDim.x;
    for (int i = blockIdx.x * blockDim.x + threadIdx.x; i < npairs; i += stride) {
        float2 v = ((const float2*)x)[i];
        xb[i] = packbf(v.x, v.y);
    }
}

// ---------------- fused gather-mean-conv: out = relu(mean @ Wl + b + xdst @ Wr) ----------------
// block = 256 = 4 waves, one dst row per wave; weights as packed bf16 pairs in LDS (64KB)
// xsrc rows are packed bf16 pairs [nsrc][64]; out likewise [nrows][64]
template<bool XDST_BF>
__global__ __launch_bounds__(256) void conv_gather_kernel(
    const unsigned* __restrict__ xsrc,
    const unsigned* __restrict__ row_ptr,
    const int* __restrict__ nbr,
    const void* __restrict__ xdst_,
    const float* __restrict__ Wl,
    const float* __restrict__ Wr,
    const float* __restrict__ bias,
    unsigned* __restrict__ out, int nrows)
{
    __shared__ unsigned sWl[D][D / 2];   // sWl[k][t] = bf16 pair (Wl[k][2t], Wl[k][2t+1])
    __shared__ unsigned sWr[D][D / 2];
    for (int i = threadIdx.x; i < D * D / 2; i += 256) {
        float2 wl = ((const float2*)Wl)[i];
        ((unsigned*)sWl)[i] = packbf(wl.x, wl.y);
        float2 wr = ((const float2*)Wr)[i];
        ((unsigned*)sWr)[i] = packbf(wr.x, wr.y);
    }
    __syncthreads();

    int wave = threadIdx.x >> 6;
    int lane = threadIdx.x & 63;
    float2 bias2 = ((const float2*)bias)[lane];

    for (int r = blockIdx.x * 4 + wave; r < nrows; r += gridDim.x * 4) {
        unsigned beg = row_ptr[r], end = row_ptr[r + 1];
        float a0 = 0.0f, a1 = 0.0f;
        unsigned u = beg;
        for (; u + 2 <= end; u += 2) {
            int j0 = nbr[u], j1 = nbr[u + 1];
            unsigned p0 = xsrc[(size_t)j0 * 64 + lane];
            unsigned p1 = xsrc[(size_t)j1 * 64 + lane];
            a0 += bflo(p0) + bflo(p1);
            a1 += bfhi(p0) + bfhi(p1);
        }
        if (u < end) {
            int j = nbr[u];
            unsigned p = xsrc[(size_t)j * 64 + lane];
            a0 += bflo(p); a1 += bfhi(p);
        }
        unsigned c = end - beg;
        float inv = 1.0f / (float)(c ? c : 1u);
        float m0 = a0 * inv, m1 = a1 * inv;

        float x0, x1;
        if (XDST_BF) {
            unsigned xp = ((const unsigned*)xdst_)[(size_t)r * 64 + lane];
            x0 = bflo(xp); x1 = bfhi(xp);
        } else {
            float2 x2 = ((const float2*)xdst_)[(size_t)r * 64 + lane];
            x0 = x2.x; x1 = x2.y;
        }
        float acc0 = bias2.x, acc1 = bias2.y;
#pragma unroll 8
        for (int k2 = 0; k2 < 64; ++k2) {
            float ma = __shfl(m0, k2, 64);
            float mb = __shfl(m1, k2, 64);
            float xa = __shfl(x0, k2, 64);
            float xb = __shfl(x1, k2, 64);
            unsigned wl0 = sWl[2 * k2][lane];
            unsigned wl1 = sWl[2 * k2 + 1][lane];
            unsigned wr0 = sWr[2 * k2][lane];
            unsigned wr1 = sWr[2 * k2 + 1][lane];
            acc0 += ma * bflo(wl0) + mb * bflo(wl1) + xa * bflo(wr0) + xb * bflo(wr1);
            acc1 += ma * bfhi(wl0) + mb * bfhi(wl1) + xa * bfhi(wr0) + xb * bfhi(wr1);
        }
        out[(size_t)r * 64 + lane] = packbf(fmaxf(acc0, 0.0f), fmaxf(acc1, 0.0f));
    }
}

// ---------------- final: out = h @ Wlin + blin (128 -> 64), f32 out ----------------
__global__ __launch_bounds__(256) void final_kernel(const unsigned* __restrict__ h,
                                                    const float* __restrict__ W,
                                                    const float* __restrict__ b,
                                                    float* __restrict__ out, int nrows)
{
    __shared__ unsigned short sW[D * OUTC];   // bf16 bits, 16KB
    for (int i = threadIdx.x; i < D * OUTC; i += 256) sW[i] = f2bf(W[i]);
    __syncthreads();

    int wave = threadIdx.x >> 6;
    int lane = threadIdx.x & 63;
    float bc = b[lane];

    for (int r = blockIdx.x * 4 + wave; r < nrows; r += gridDim.x * 4) {
        unsigned hp = h[(size_t)r * 64 + lane];
        float h0 = bflo(hp), h1 = bfhi(hp);
        float acc = bc;
#pragma unroll 8
        for (int k2 = 0; k2 < 64; ++k2) {
            float a  = __shfl(h0, k2, 64);
            float bb = __shfl(h1, k2, 64);
            acc += a  * __uint_as_float((unsigned)sW[(2 * k2) * OUTC + lane] << 16);
            acc += bb * __uint_as_float((unsigned)sW[(2 * k2 + 1) * OUTC + lane] << 16);
        }
        out[(size_t)r * OUTC + lane] = acc;
    }
}

extern "C" void kernel_launch(void* const* d_in, const int* in_sizes, int n_in,
                              void* d_out, int out_size, void* d_ws, size_t ws_size,
                              hipStream_t stream)
{
    const float* x_taxon = (const float*)d_in[0];
    const float* x_sotu  = (const float*)d_in[1];
    const int* hp_src = (const int*)d_in[2];
    const int* hp_dst = (const int*)d_in[3];
    const int* rh_src = (const int*)d_in[4];
    const int* rh_dst = (const int*)d_in[5];
    const float* W1l = (const float*)d_in[6];
    const float* W1r = (const float*)d_in[7];
    const float* b1  = (const float*)d_in[8];
    const float* W2l = (const float*)d_in[9];
    const float* W2r = (const float*)d_in[10];
    const float* b2  = (const float*)d_in[11];
    const float* W3l = (const float*)d_in[12];
    const float* W3r = (const float*)d_in[13];
    const float* b3  = (const float*)d_in[14];
    const float* Wlin = (const float*)d_in[15];
    const float* blin = (const float*)d_in[16];
    float* out = (float*)d_out;

    // workspace layout (bytes):
    //   [0          ,  25,600,000) xt_bf     bf16-pairs [100000][64]
    //   [25,600,000 ,  51,200,000) taxon_h   bf16-pairs
    //   [51,200,000 , 102,400,000) sotu_h    bf16-pairs
    //   [102,400,000, 153,600,000) h2        bf16-pairs
    //   [153,600,000, 154,000,256) row_ptr_t u32 [100001]
    //   [154,000,384, 154,800,640) row_ptr_s u32 [200001]
    //   [154,800,640, 155,200,640) cnt_t / cursor_t u32 [100000]
    //   [155,200,640, 156,000,640) cnt_s / cursor_s u32 [200000]
    //   [156,000,640, 156,004,736) bsum u32 [1024]
    //   [156,004,736, 156,804,736) sorted_hp int [200000]
    //   [156,804,736, 164,804,736) sorted_rh int [2000000]
    char* ws = (char*)d_ws;
    unsigned* xt_bf     = (unsigned*)(ws);
    unsigned* taxon_h   = (unsigned*)(ws + 25600000);
    unsigned* sotu_h    = (unsigned*)(ws + 51200000);
    unsigned* h2        = (unsigned*)(ws + 102400000);
    unsigned* row_ptr_t = (unsigned*)(ws + 153600000);
    unsigned* row_ptr_s = (unsigned*)(ws + 154000384);
    unsigned* cnt_t     = (unsigned*)(ws + 154800640);
    unsigned* cnt_s     = (unsigned*)(ws + 155200640);
    unsigned* bsum      = (unsigned*)(ws + 156000640);
    int*      sorted_hp = (int*)(ws + 156004736);
    int*      sorted_rh = (int*)(ws + 156804736);

    // zero the degree counters only (1.2 MB)
    hipMemsetAsync(cnt_t, 0, 400000 + 800000, stream);

    count_kernel<<<4300, 256, 0, stream>>>(hp_dst, rh_dst, cnt_t, cnt_s);

    // CSR for hp (n = N_TAXON)
    {
        int nb = (N_TAXON + 255) / 256;   // 391
        scanA_kernel<<<nb, 256, 0, stream>>>(cnt_t, bsum, N_TAXON);
        scanB_kernel<<<1, 1024, 0, stream>>>(bsum, nb, row_ptr_t + N_TAXON);
        scanC_kernel<<<nb, 256, 0, stream>>>(cnt_t, bsum, row_ptr_t, N_TAXON);
        hipMemcpyAsync(cnt_t, row_ptr_t, (size_t)N_TAXON * 4, hipMemcpyDeviceToDevice, stream);
        fill_kernel<<<782, 256, 0, stream>>>(hp_src, hp_dst, cnt_t, sorted_hp, E_HP);
    }
    // CSR for rh (n = N_SOTU) — shared by conv2 and conv3
    {
        int nb = (N_SOTU + 255) / 256;    // 782
        scanA_kernel<<<nb, 256, 0, stream>>>(cnt_s, bsum, N_SOTU);
        scanB_kernel<<<1, 1024, 0, stream>>>(bsum, nb, row_ptr_s + N_SOTU);
        scanC_kernel<<<nb, 256, 0, stream>>>(cnt_s, bsum, row_ptr_s, N_SOTU);
        hipMemcpyAsync(cnt_s, row_ptr_s, (size_t)N_SOTU * 4, hipMemcpyDeviceToDevice, stream);
        fill_kernel<<<2048, 256, 0, stream>>>(rh_src, rh_dst, cnt_s, sorted_rh, E_RH);
    }

    // cast x_taxon to bf16 pairs (gather payload)
    cast_kernel<<<6400, 256, 0, stream>>>(x_taxon, xt_bf, N_TAXON * 64);

    // conv1: taxon_h = relu(mean_hp(x_taxon) @ W1l + b1 + x_taxon @ W1r)
    conv_gather_kernel<false><<<(N_TAXON + 3) / 4, 256, 0, stream>>>(
        xt_bf, row_ptr_t, sorted_hp, x_taxon, W1l, W1r, b1, taxon_h, N_TAXON);
    // conv2: sotu_h = relu(mean_rh(x_taxon) @ W2l + b2 + x_sotu @ W2r)
    conv_gather_kernel<false><<<(N_SOTU + 3) / 4, 256, 0, stream>>>(
        xt_bf, row_ptr_s, sorted_rh, x_sotu, W2l, W2r, b2, sotu_h, N_SOTU);
    // conv3: h2 = relu(mean_rh(taxon_h) @ W3l + b3 + sotu_h @ W3r)
    conv_gather_kernel<true><<<(N_SOTU + 3) / 4, 256, 0, stream>>>(
        taxon_h, row_ptr_s, sorted_rh, sotu_h, W3l, W3r, b3, h2, N_SOTU);

    // final linear (f32 out)
    final_kernel<<<(N_SOTU + 3) / 4, 256, 0, stream>>>(h2, Wlin, blin, out, N_SOTU);
}

// Round 4
// 741.611 us; speedup vs baseline: 7.8420x; 4.9553x over previous
//
#include <hip/hip_runtime.h>
#include <hip/hip_bf16.h>

#define D 128
#define N_TAXON 100000
#define N_SOTU 200000
#define E_HP 200000
#define E_RH 2000000
#define OUTC 64

typedef __hip_bfloat16 bf16;
typedef __bf16 bf16v8 __attribute__((ext_vector_type(8)));
typedef float f32x4 __attribute__((ext_vector_type(4)));
typedef int i32x4 __attribute__((ext_vector_type(4)));
typedef unsigned u32x2 __attribute__((ext_vector_type(2)));

union Frag { i32x4 i; bf16v8 v; };

__device__ __forceinline__ float bflo(unsigned u) { return __uint_as_float(u << 16); }
__device__ __forceinline__ float bfhi(unsigned u) { return __uint_as_float(u & 0xffff0000u); }

__device__ __forceinline__ unsigned short f2bf(float x) {
    unsigned u = __float_as_uint(x);
    unsigned r = (u + 0x7fffu + ((u >> 16) & 1u)) >> 16;   // round-to-nearest-even
    return (unsigned short)r;
}
__device__ __forceinline__ unsigned packbf(float a, float b) {
    return (unsigned)f2bf(a) | ((unsigned)f2bf(b) << 16);
}

// ---------------- count per-dst degree ----------------
__global__ __launch_bounds__(256) void count_kernel(const int* __restrict__ hp_dst,
                                                    const int* __restrict__ rh_dst,
                                                    unsigned* cnt_t, unsigned* cnt_s)
{
    int stride = gridDim.x * blockDim.x;
    for (int i = blockIdx.x * blockDim.x + threadIdx.x; i < E_HP + E_RH; i += stride) {
        if (i < E_HP) atomicAdd(&cnt_t[hp_dst[i]], 1u);
        else          atomicAdd(&cnt_s[rh_dst[i - E_HP]], 1u);
    }
}

// ---------------- 3-phase exclusive scan ----------------
__global__ __launch_bounds__(256) void scanA_kernel(const unsigned* __restrict__ cnt,
                                                    unsigned* __restrict__ bsum, int n)
{
    int lane = threadIdx.x & 63, wv = threadIdx.x >> 6;
    __shared__ unsigned ws[4];
    int i = blockIdx.x * 256 + threadIdx.x;
    unsigned v = (i < n) ? cnt[i] : 0u;
    for (int off = 1; off < 64; off <<= 1) v += __shfl_xor(v, off, 64);
    if (lane == 0) ws[wv] = v;
    __syncthreads();
    if (threadIdx.x == 0) bsum[blockIdx.x] = ws[0] + ws[1] + ws[2] + ws[3];
}

__global__ __launch_bounds__(1024) void scanB_kernel(unsigned* __restrict__ bsum, int nb,
                                                     unsigned* __restrict__ total_out)
{
    int lane = threadIdx.x & 63, wv = threadIdx.x >> 6;
    __shared__ unsigned wsum[16];
    int i = threadIdx.x;
    unsigned v = (i < nb) ? bsum[i] : 0u;
    unsigned s = v;
    for (int off = 1; off < 64; off <<= 1) {
        unsigned t = __shfl_up(s, off, 64);
        if (lane >= off) s += t;
    }
    if (lane == 63) wsum[wv] = s;
    __syncthreads();
    unsigned woff = 0, tot = 0;
    for (int w = 0; w < 16; ++w) { if (w < wv) woff += wsum[w]; tot += wsum[w]; }
    if (i < nb) bsum[i] = woff + s - v;    // exclusive
    if (threadIdx.x == 0) *total_out = tot;
}

__global__ __launch_bounds__(256) void scanC_kernel(const unsigned* __restrict__ cnt,
                                                    const unsigned* __restrict__ bsum,
                                                    unsigned* __restrict__ row_ptr, int n)
{
    int lane = threadIdx.x & 63, wv = threadIdx.x >> 6;
    __shared__ unsigned wsum[4];
    int i = blockIdx.x * 256 + threadIdx.x;
    unsigned v = (i < n) ? cnt[i] : 0u;
    unsigned s = v;
    for (int off = 1; off < 64; off <<= 1) {
        unsigned t = __shfl_up(s, off, 64);
        if (lane >= off) s += t;
    }
    if (lane == 63) wsum[wv] = s;
    __syncthreads();
    unsigned woff = bsum[blockIdx.x];
    for (int w = 0; w < wv; ++w) woff += wsum[w];
    if (i < n) row_ptr[i] = woff + s - v;
}

// ---------------- fill CSR neighbor lists via atomic cursor ----------------
__global__ __launch_bounds__(256) void fill_kernel(const int* __restrict__ src,
                                                   const int* __restrict__ dst,
                                                   unsigned* __restrict__ cursor,
                                                   int* __restrict__ sorted, int n)
{
    int stride = gridDim.x * blockDim.x;
    for (int i = blockIdx.x * blockDim.x + threadIdx.x; i < n; i += stride) {
        unsigned pos = atomicAdd(&cursor[dst[i]], 1u);
        sorted[pos] = src[i];
    }
}

// ---------------- cast f32 rows -> packed bf16 pairs ----------------
__global__ __launch_bounds__(256) void cast_kernel(const float* __restrict__ x,
                                                   unsigned* __restrict__ xb, int npairs)
{
    int stride = gridDim.x * blockDim.x;
    for (int i = blockIdx.x * blockDim.x + threadIdx.x; i < npairs; i += stride) {
        float2 v = ((const float2*)x)[i];
        xb[i] = packbf(v.x, v.y);
    }
}

// ---------------- weight prep: Wt[col][k] = bf16(W[k][col]), XOR-swizzled ----------------
__global__ __launch_bounds__(256) void wprep_kernel(const float* __restrict__ W,
                                                    unsigned short* __restrict__ Wt, int N)
{
    int e = blockIdx.x * 256 + threadIdx.x;      // e = k*N + col (coalesced read)
    if (e >= 128 * N) return;
    int k = e / N, col = e - k * N;
    Wt[(col * 128 + k) ^ ((col & 7) << 3)] = f2bf(W[e]);
}

// ---------------- MFMA GEMM: Y[M][BN] = Xb[M][128] @ W[128][BN] (+bias) ----------------
// block = 256 = 4 waves; wave computes 16 rows x BN cols.
// swapped-operand mfma: a = W-frag (M-role = out col), b = X-frag (N-role = out row)
// -> lane holds out[row = base+ln][cols cf*16 + 4g + 0..3] in acc[cf][0..3]
template<int BN, bool F32OUT>
__global__ __launch_bounds__(256) void gemm_kernel(
    const unsigned* __restrict__ Xb,          // [M][64] u32 bf16-pairs (row-major, K=128)
    const unsigned short* __restrict__ Wt,    // pre-swizzled bf16 image [BN][128]
    const float* __restrict__ biasv,          // [BN] or nullptr
    void* __restrict__ Yout, int M)
{
    constexpr int NCF = BN / 16;
    __shared__ char sW[BN * 256];
    for (int c = threadIdx.x; c < BN * 16; c += 256)
        ((i32x4*)sW)[c] = ((const i32x4*)Wt)[c];
    __syncthreads();

    int wave = threadIdx.x >> 6;
    int lane = threadIdx.x & 63;
    int ln = lane & 15, g = lane >> 4;
    int row = blockIdx.x * 64 + wave * 16 + ln;
    int rl = row < M ? row : M - 1;
    int swz = (ln & 7) << 4;

    f32x4 acc[NCF];
#pragma unroll
    for (int cf = 0; cf < NCF; ++cf) {
        if (F32OUT && biasv != nullptr) {
            f32x4 bv = ((const f32x4*)biasv)[cf * 4 + g];
            acc[cf] = bv;
        } else {
            for (int e = 0; e < 4; ++e) acc[cf][e] = 0.0f;
        }
    }

    const i32x4* xrow = (const i32x4*)(Xb + (size_t)rl * 64);
#pragma unroll
    for (int ks = 0; ks < 4; ++ks) {
        Frag xf; xf.i = xrow[ks * 4 + g];
#pragma unroll
        for (int cf = 0; cf < NCF; ++cf) {
            Frag wf;
            wf.i = *(const i32x4*)(sW + ((((cf * 16 + ln) << 8) + (ks << 6) + (g << 4)) ^ swz));
            acc[cf] = __builtin_amdgcn_mfma_f32_16x16x32_bf16(wf.v, xf.v, acc[cf], 0, 0, 0);
        }
    }

    if (row < M) {
        if (F32OUT) {
            float* orow = (float*)Yout + (size_t)row * BN;
#pragma unroll
            for (int cf = 0; cf < NCF; ++cf)
                *(f32x4*)(orow + cf * 16 + 4 * g) = acc[cf];
        } else {
            unsigned* orow = (unsigned*)Yout + (size_t)row * (BN / 2);
#pragma unroll
            for (int cf = 0; cf < NCF; ++cf) {
                u32x2 o;
                o.x = packbf(acc[cf][0], acc[cf][1]);
                o.y = packbf(acc[cf][2], acc[cf][3]);
                *(u32x2*)(orow + cf * 8 + g * 2) = o;
            }
        }
    }
}

// ---------------- aggregate: out[r] = relu(mean_nbr(Y) + Z[r] + bias), bf16 pairs ----------------
__global__ __launch_bounds__(256) void agg_kernel(
    const unsigned* __restrict__ Y,     // [*][64] bf16 pairs
    const unsigned* __restrict__ rp,    // row_ptr [nrows+1]
    const int* __restrict__ nbr,
    const unsigned* __restrict__ Z,     // [nrows][64]
    const float* __restrict__ bias,     // [128]
    unsigned* __restrict__ outb,        // [nrows][64]
    int nrows)
{
    int wave = threadIdx.x >> 6, lane = threadIdx.x & 63;
    int r = blockIdx.x * 4 + wave;
    if (r >= nrows) return;
    unsigned beg = rp[r], end = rp[r + 1];
    float a0 = 0.f, a1 = 0.f;
    unsigned u = beg;
    for (; u + 4 <= end; u += 4) {
        int j0 = nbr[u], j1 = nbr[u + 1], j2 = nbr[u + 2], j3 = nbr[u + 3];
        unsigned p0 = Y[(size_t)j0 * 64 + lane];
        unsigned p1 = Y[(size_t)j1 * 64 + lane];
        unsigned p2 = Y[(size_t)j2 * 64 + lane];
        unsigned p3 = Y[(size_t)j3 * 64 + lane];
        a0 += bflo(p0) + bflo(p1) + bflo(p2) + bflo(p3);
        a1 += bfhi(p0) + bfhi(p1) + bfhi(p2) + bfhi(p3);
    }
    for (; u < end; ++u) {
        unsigned p = Y[(size_t)nbr[u] * 64 + lane];
        a0 += bflo(p); a1 += bfhi(p);
    }
    unsigned c = end - beg;
    float inv = 1.f / (float)(c ? c : 1u);
    unsigned zp = Z[(size_t)r * 64 + lane];
    float2 b2 = ((const float2*)bias)[lane];
    float r0 = fmaxf(a0 * inv + bflo(zp) + b2.x, 0.f);
    float r1 = fmaxf(a1 * inv + bfhi(zp) + b2.y, 0.f);
    outb[(size_t)r * 64 + lane] = packbf(r0, r1);
}

extern "C" void kernel_launch(void* const* d_in, const int* in_sizes, int n_in,
                              void* d_out, int out_size, void* d_ws, size_t ws_size,
                              hipStream_t stream)
{
    const float* x_taxon = (const float*)d_in[0];
    const float* x_sotu  = (const float*)d_in[1];
    const int* hp_src = (const int*)d_in[2];
    const int* hp_dst = (const int*)d_in[3];
    const int* rh_src = (const int*)d_in[4];
    const int* rh_dst = (const int*)d_in[5];
    const float* W1l = (const float*)d_in[6];
    const float* W1r = (const float*)d_in[7];
    const float* b1  = (const float*)d_in[8];
    const float* W2l = (const float*)d_in[9];
    const float* W2r = (const float*)d_in[10];
    const float* b2  = (const float*)d_in[11];
    const float* W3l = (const float*)d_in[12];
    const float* W3r = (const float*)d_in[13];
    const float* b3  = (const float*)d_in[14];
    const float* Wlin = (const float*)d_in[15];
    const float* blin = (const float*)d_in[16];
    float* out = (float*)d_out;

    // ---- workspace layout (bytes), peak ~216.3 MB ----
    char* ws = (char*)d_ws;
    unsigned* xs_bf   = (unsigned*)(ws);                 // 51.2MB -> sotu_h -> h2
    unsigned* xt_bf   = (unsigned*)(ws + 51200000);      // 25.6MB
    unsigned* y1      = (unsigned*)(ws + 76800000);      // 25.6MB -> y2 (51.2 w/ z1) -> z3
    unsigned* z1      = (unsigned*)(ws + 102400000);     // 25.6MB
    unsigned* taxon_h = (unsigned*)(ws + 128000000);     // 25.6MB
    unsigned* z2      = (unsigned*)(ws + 153600000);     // 51.2MB -> y3
    unsigned* y2      = y1;                              // overlays y1+z1 after agg1
    unsigned* z3      = y1;                              // overlays y2 after agg2
    unsigned* y3      = z2;                              // overlays z2 after agg2
    unsigned* sotu_h  = xs_bf;                           // after GEMM Z2
    unsigned* h2      = xs_bf;                           // after GEMM Z3

    unsigned* row_ptr_t = (unsigned*)(ws + 204800000);   // [100001]
    unsigned* row_ptr_s = (unsigned*)(ws + 205200128);   // [200001]
    unsigned* cnt_t     = (unsigned*)(ws + 206000384);   // [100000]
    unsigned* cnt_s     = (unsigned*)(ws + 206400384);   // [200000]
    unsigned* bsum      = (unsigned*)(ws + 207200384);   // [1024]
    int*      sorted_hp = (int*)(ws + 207204480);        // [200000]
    int*      sorted_rh = (int*)(ws + 208004480);        // [2000000]
    unsigned short* wtbase = (unsigned short*)(ws + 216004480);
    unsigned short* Wt1l = wtbase;                       // 7 x 16K bf16 (Wlin 8K)
    unsigned short* Wt1r = wtbase + 16384;
    unsigned short* Wt2l = wtbase + 32768;
    unsigned short* Wt2r = wtbase + 49152;
    unsigned short* Wt3l = wtbase + 65536;
    unsigned short* Wt3r = wtbase + 81920;
    unsigned short* Wtlin = wtbase + 98304;

    // zero degree counters (1.2MB)
    hipMemsetAsync(cnt_t, 0, 1200000, stream);

    count_kernel<<<4300, 256, 0, stream>>>(hp_dst, rh_dst, cnt_t, cnt_s);

    // CSR hp (n = N_TAXON)
    {
        int nb = (N_TAXON + 255) / 256;   // 391
        scanA_kernel<<<nb, 256, 0, stream>>>(cnt_t, bsum, N_TAXON);
        scanB_kernel<<<1, 1024, 0, stream>>>(bsum, nb, row_ptr_t + N_TAXON);
        scanC_kernel<<<nb, 256, 0, stream>>>(cnt_t, bsum, row_ptr_t, N_TAXON);
        hipMemcpyAsync(cnt_t, row_ptr_t, (size_t)N_TAXON * 4, hipMemcpyDeviceToDevice, stream);
        fill_kernel<<<782, 256, 0, stream>>>(hp_src, hp_dst, cnt_t, sorted_hp, E_HP);
    }
    // CSR rh (n = N_SOTU), shared by layers 2 and 3
    {
        int nb = (N_SOTU + 255) / 256;    // 782
        scanA_kernel<<<nb, 256, 0, stream>>>(cnt_s, bsum, N_SOTU);
        scanB_kernel<<<1, 1024, 0, stream>>>(bsum, nb, row_ptr_s + N_SOTU);
        scanC_kernel<<<nb, 256, 0, stream>>>(cnt_s, bsum, row_ptr_s, N_SOTU);
        hipMemcpyAsync(cnt_s, row_ptr_s, (size_t)N_SOTU * 4, hipMemcpyDeviceToDevice, stream);
        fill_kernel<<<2048, 256, 0, stream>>>(rh_src, rh_dst, cnt_s, sorted_rh, E_RH);
    }

    // casts
    cast_kernel<<<(N_TAXON * 64 + 255) / 256, 256, 0, stream>>>(x_taxon, xt_bf, N_TAXON * 64);
    cast_kernel<<<(N_SOTU * 64 + 255) / 256, 256, 0, stream>>>(x_sotu, xs_bf, N_SOTU * 64);

    // weight prep (transpose + bf16 + swizzle)
    wprep_kernel<<<64, 256, 0, stream>>>(W1l, Wt1l, 128);
    wprep_kernel<<<64, 256, 0, stream>>>(W1r, Wt1r, 128);
    wprep_kernel<<<64, 256, 0, stream>>>(W2l, Wt2l, 128);
    wprep_kernel<<<64, 256, 0, stream>>>(W2r, Wt2r, 128);
    wprep_kernel<<<64, 256, 0, stream>>>(W3l, Wt3l, 128);
    wprep_kernel<<<64, 256, 0, stream>>>(W3r, Wt3r, 128);
    wprep_kernel<<<32, 256, 0, stream>>>(Wlin, Wtlin, 64);

    // ---- layer 1 (taxon -> taxon over hp) ----
    gemm_kernel<128, false><<<(N_TAXON + 63) / 64, 256, 0, stream>>>(xt_bf, Wt1l, nullptr, y1, N_TAXON);
    gemm_kernel<128, false><<<(N_TAXON + 63) / 64, 256, 0, stream>>>(xt_bf, Wt1r, nullptr, z1, N_TAXON);
    agg_kernel<<<(N_TAXON + 3) / 4, 256, 0, stream>>>(y1, row_ptr_t, sorted_hp, z1, b1, taxon_h, N_TAXON);

    // ---- layer 2 (taxon -> sotu over rh) ----
    gemm_kernel<128, false><<<(N_TAXON + 63) / 64, 256, 0, stream>>>(xt_bf, Wt2l, nullptr, y2, N_TAXON);
    gemm_kernel<128, false><<<(N_SOTU + 63) / 64, 256, 0, stream>>>(xs_bf, Wt2r, nullptr, z2, N_SOTU);
    agg_kernel<<<(N_SOTU + 3) / 4, 256, 0, stream>>>(y2, row_ptr_s, sorted_rh, z2, b2, sotu_h, N_SOTU);

    // ---- layer 3 (taxon_h -> sotu over rh) ----
    gemm_kernel<128, false><<<(N_TAXON + 63) / 64, 256, 0, stream>>>(taxon_h, Wt3l, nullptr, y3, N_TAXON);
    gemm_kernel<128, false><<<(N_SOTU + 63) / 64, 256, 0, stream>>>(sotu_h, Wt3r, nullptr, z3, N_SOTU);
    agg_kernel<<<(N_SOTU + 3) / 4, 256, 0, stream>>>(y3, row_ptr_s, sorted_rh, z3, b3, h2, N_SOTU);

    // ---- final linear (f32 out, bias in GEMM) ----
    gemm_kernel<64, true><<<(N_SOTU + 63) / 64, 256, 0, stream>>>(h2, Wtlin, blin, out, N_SOTU);
}

// Round 5
// 668.060 us; speedup vs baseline: 8.7053x; 1.1101x over previous
//
#include <hip/hip_runtime.h>
#include <hip/hip_bf16.h>

#define D 128
#define N_TAXON 100000
#define N_SOTU 200000
#define E_HP 200000
#define E_RH 2000000
#define OUTC 64
#define NBUCK 25      // ceil(N_SOTU / 8192)
#define BSHIFT 13

typedef __hip_bfloat16 bf16;
typedef __bf16 bf16v8 __attribute__((ext_vector_type(8)));
typedef float f32x4 __attribute__((ext_vector_type(4)));
typedef int i32x4 __attribute__((ext_vector_type(4)));
typedef unsigned u32x2 __attribute__((ext_vector_type(2)));

union Frag { i32x4 i; bf16v8 v; };

__device__ __forceinline__ float bflo(unsigned u) { return __uint_as_float(u << 16); }
__device__ __forceinline__ float bfhi(unsigned u) { return __uint_as_float(u & 0xffff0000u); }

__device__ __forceinline__ unsigned short f2bf(float x) {
    unsigned u = __float_as_uint(x);
    unsigned r = (u + 0x7fffu + ((u >> 16) & 1u)) >> 16;   // round-to-nearest-even
    return (unsigned short)r;
}
__device__ __forceinline__ unsigned packbf(float a, float b) {
    return (unsigned)f2bf(a) | ((unsigned)f2bf(b) << 16);
}

// ---------------- hp: per-dst degree ----------------
__global__ __launch_bounds__(256) void count_hp_kernel(const int* __restrict__ dst, unsigned* cnt)
{
    int stride = gridDim.x * 256;
    for (int i = blockIdx.x * 256 + threadIdx.x; i < E_HP; i += stride)
        atomicAdd(&cnt[dst[i]], 1u);
}

// ---------------- rh: bucket histogram (dst>>BSHIFT) ----------------
__global__ __launch_bounds__(256) void countB_kernel(const int* __restrict__ dst,
                                                     unsigned* __restrict__ bcnt, int n)
{
    __shared__ unsigned hist[NBUCK];
    for (int i = threadIdx.x; i < NBUCK; i += 256) hist[i] = 0;
    __syncthreads();
    int stride = gridDim.x * 256;
    for (int e = blockIdx.x * 256 + threadIdx.x; e < n; e += stride)
        atomicAdd(&hist[dst[e] >> BSHIFT], 1u);
    __syncthreads();
    if (threadIdx.x < NBUCK) atomicAdd(&bcnt[threadIdx.x], hist[threadIdx.x]);
}

__global__ void scan25_kernel(const unsigned* __restrict__ bcnt, unsigned* __restrict__ bcursor)
{
    if (threadIdx.x == 0) {
        unsigned acc = 0;
        for (int b = 0; b < NBUCK; ++b) { bcursor[b] = acc; acc += bcnt[b]; }
    }
}

// ---------------- rh: partition edges into dst-buckets, (dst<<32)|src pairs ----------------
__global__ __launch_bounds__(256) void partition_kernel(
    const int* __restrict__ src, const int* __restrict__ dst,
    unsigned* __restrict__ bcursor, unsigned long long* __restrict__ ebuf, int n)
{
    __shared__ unsigned hist[NBUCK];
    __shared__ unsigned lcur[NBUCK];
    int base = blockIdx.x * 2048;
    for (int i = threadIdx.x; i < NBUCK; i += 256) hist[i] = 0;
    __syncthreads();
    int s[8], d[8];
#pragma unroll
    for (int k = 0; k < 8; ++k) {
        int e = base + k * 256 + threadIdx.x;
        if (e < n) {
            s[k] = src[e]; d[k] = dst[e];
            atomicAdd(&hist[d[k] >> BSHIFT], 1u);
        } else d[k] = -1;
    }
    __syncthreads();
    if (threadIdx.x < NBUCK)
        lcur[threadIdx.x] = atomicAdd(&bcursor[threadIdx.x], hist[threadIdx.x]);
    __syncthreads();
#pragma unroll
    for (int k = 0; k < 8; ++k) {
        if (d[k] >= 0) {
            unsigned slot = atomicAdd(&lcur[d[k] >> BSHIFT], 1u);
            ebuf[slot] = ((unsigned long long)(unsigned)d[k] << 32) | (unsigned)s[k];
        }
    }
}

// ---------------- rh: per-dst degree from bucket-clustered ebuf ----------------
__global__ __launch_bounds__(256) void count2_kernel(const unsigned long long* __restrict__ ebuf,
                                                     unsigned* __restrict__ cnt, int n)
{
    int stride = gridDim.x * 256;
    for (int e = blockIdx.x * 256 + threadIdx.x; e < n; e += stride)
        atomicAdd(&cnt[(unsigned)(ebuf[e] >> 32)], 1u);
}

// ---------------- 3-phase exclusive scan ----------------
__global__ __launch_bounds__(256) void scanA_kernel(const unsigned* __restrict__ cnt,
                                                    unsigned* __restrict__ bsum, int n)
{
    int lane = threadIdx.x & 63, wv = threadIdx.x >> 6;
    __shared__ unsigned ws[4];
    int i = blockIdx.x * 256 + threadIdx.x;
    unsigned v = (i < n) ? cnt[i] : 0u;
    for (int off = 1; off < 64; off <<= 1) v += __shfl_xor(v, off, 64);
    if (lane == 0) ws[wv] = v;
    __syncthreads();
    if (threadIdx.x == 0) bsum[blockIdx.x] = ws[0] + ws[1] + ws[2] + ws[3];
}

__global__ __launch_bounds__(1024) void scanB_kernel(unsigned* __restrict__ bsum, int nb,
                                                     unsigned* __restrict__ total_out)
{
    int lane = threadIdx.x & 63, wv = threadIdx.x >> 6;
    __shared__ unsigned wsum[16];
    int i = threadIdx.x;
    unsigned v = (i < nb) ? bsum[i] : 0u;
    unsigned s = v;
    for (int off = 1; off < 64; off <<= 1) {
        unsigned t = __shfl_up(s, off, 64);
        if (lane >= off) s += t;
    }
    if (lane == 63) wsum[wv] = s;
    __syncthreads();
    unsigned woff = 0, tot = 0;
    for (int w = 0; w < 16; ++w) { if (w < wv) woff += wsum[w]; tot += wsum[w]; }
    if (i < nb) bsum[i] = woff + s - v;    // exclusive
    if (threadIdx.x == 0) *total_out = tot;
}

__global__ __launch_bounds__(256) void scanC_kernel(const unsigned* __restrict__ cnt,
                                                    const unsigned* __restrict__ bsum,
                                                    unsigned* __restrict__ row_ptr, int n)
{
    int lane = threadIdx.x & 63, wv = threadIdx.x >> 6;
    __shared__ unsigned wsum[4];
    int i = blockIdx.x * 256 + threadIdx.x;
    unsigned v = (i < n) ? cnt[i] : 0u;
    unsigned s = v;
    for (int off = 1; off < 64; off <<= 1) {
        unsigned t = __shfl_up(s, off, 64);
        if (lane >= off) s += t;
    }
    if (lane == 63) wsum[wv] = s;
    __syncthreads();
    unsigned woff = bsum[blockIdx.x];
    for (int w = 0; w < wv; ++w) woff += wsum[w];
    if (i < n) row_ptr[i] = woff + s - v;
}

// ---------------- CSR fill: hp (raw edges), rh (from ebuf) ----------------
__global__ __launch_bounds__(256) void fill_kernel(const int* __restrict__ src,
                                                   const int* __restrict__ dst,
                                                   unsigned* __restrict__ cursor,
                                                   int* __restrict__ sorted, int n)
{
    int stride = gridDim.x * blockDim.x;
    for (int i = blockIdx.x * blockDim.x + threadIdx.x; i < n; i += stride) {
        unsigned pos = atomicAdd(&cursor[dst[i]], 1u);
        sorted[pos] = src[i];
    }
}

__global__ __launch_bounds__(256) void fill2_kernel(const unsigned long long* __restrict__ ebuf,
                                                    unsigned* __restrict__ cursor,
                                                    int* __restrict__ sorted, int n)
{
    int stride = gridDim.x * 256;
    for (int e = blockIdx.x * 256 + threadIdx.x; e < n; e += stride) {
        unsigned long long v = ebuf[e];
        unsigned pos = atomicAdd(&cursor[(unsigned)(v >> 32)], 1u);
        sorted[pos] = (int)(unsigned)v;
    }
}

// ---------------- weight prep: Wt[col][k] = bf16(W[k][col]), XOR-swizzled ----------------
__global__ __launch_bounds__(256) void wprep_kernel(const float* __restrict__ W,
                                                    unsigned short* __restrict__ Wt, int N)
{
    int e = blockIdx.x * 256 + threadIdx.x;      // e = k*N + col (coalesced read)
    if (e >= 128 * N) return;
    int k = e / N, col = e - k * N;
    Wt[(col * 128 + k) ^ ((col & 7) << 3)] = f2bf(W[e]);
}

// ---------------- MFMA GEMM: Y[M][BN] = X[M][128] @ W[128][BN] ----------------
// EPI 0: bf16-pair out (stride/offset in u32)       EPI 1: f32 out + bias
// EPI 2: bf16-pair out = relu(acc + mean3 + bias)
template<int BN, bool F32A, int EPI>
__global__ __launch_bounds__(256) void gemm_kernel(
    const void* __restrict__ Xin,
    const unsigned short* __restrict__ Wt,
    const float* __restrict__ biasv,
    const unsigned* __restrict__ mean3,
    void* __restrict__ Yout, int ostride, int ooff, int M)
{
    constexpr int NCF = BN / 16;
    __shared__ char sW[BN * 256];
    for (int c = threadIdx.x; c < BN * 16; c += 256)
        ((i32x4*)sW)[c] = ((const i32x4*)Wt)[c];
    __syncthreads();

    int wave = threadIdx.x >> 6;
    int lane = threadIdx.x & 63;
    int ln = lane & 15, g = lane >> 4;
    int row = blockIdx.x * 64 + wave * 16 + ln;
    int rl = row < M ? row : M - 1;
    int swz = (ln & 7) << 4;

    f32x4 acc[NCF];
#pragma unroll
    for (int cf = 0; cf < NCF; ++cf) {
        if (EPI == 1) acc[cf] = ((const f32x4*)biasv)[cf * 4 + g];
        else for (int e = 0; e < 4; ++e) acc[cf][e] = 0.0f;
    }

#pragma unroll
    for (int ks = 0; ks < 4; ++ks) {
        Frag xf;
        if (F32A) {
            const f32x4* xr = (const f32x4*)((const float*)Xin + (size_t)rl * 128);
            f32x4 fa = xr[ks * 8 + g * 2];
            f32x4 fb = xr[ks * 8 + g * 2 + 1];
            i32x4 t = { (int)packbf(fa.x, fa.y), (int)packbf(fa.z, fa.w),
                        (int)packbf(fb.x, fb.y), (int)packbf(fb.z, fb.w) };
            xf.i = t;
        } else {
            const i32x4* xr = (const i32x4*)((const unsigned*)Xin + (size_t)rl * 64);
            xf.i = xr[ks * 4 + g];
        }
#pragma unroll
        for (int cf = 0; cf < NCF; ++cf) {
            Frag wf;
            wf.i = *(const i32x4*)(sW + ((((cf * 16 + ln) << 8) + (ks << 6) + (g << 4)) ^ swz));
            acc[cf] = __builtin_amdgcn_mfma_f32_16x16x32_bf16(wf.v, xf.v, acc[cf], 0, 0, 0);
        }
    }

    if (row < M) {
        if (EPI == 1) {
            float* orow = (float*)Yout + (size_t)row * ostride;
#pragma unroll
            for (int cf = 0; cf < NCF; ++cf)
                *(f32x4*)(orow + cf * 16 + 4 * g) = acc[cf];
        } else if (EPI == 2) {
            const unsigned* mrow = mean3 + (size_t)row * 64;
            unsigned* orow = (unsigned*)Yout + (size_t)row * ostride + ooff;
#pragma unroll
            for (int cf = 0; cf < NCF; ++cf) {
                u32x2 mp = *(const u32x2*)(mrow + cf * 8 + g * 2);
                f32x4 bv = ((const f32x4*)biasv)[cf * 4 + g];
                float o0 = fmaxf(acc[cf][0] + bflo(mp.x) + bv.x, 0.f);
                float o1 = fmaxf(acc[cf][1] + bfhi(mp.x) + bv.y, 0.f);
                float o2 = fmaxf(acc[cf][2] + bflo(mp.y) + bv.z, 0.f);
                float o3 = fmaxf(acc[cf][3] + bfhi(mp.y) + bv.w, 0.f);
                u32x2 o; o.x = packbf(o0, o1); o.y = packbf(o2, o3);
                *(u32x2*)(orow + cf * 8 + g * 2) = o;
            }
        } else {
            unsigned* orow = (unsigned*)Yout + (size_t)row * ostride + ooff;
#pragma unroll
            for (int cf = 0; cf < NCF; ++cf) {
                u32x2 o;
                o.x = packbf(acc[cf][0], acc[cf][1]);
                o.y = packbf(acc[cf][2], acc[cf][3]);
                *(u32x2*)(orow + cf * 8 + g * 2) = o;
            }
        }
    }
}

// ---------------- layer-1 aggregate: out = relu(mean_nbr(Y) + Z + bias) ----------------
__global__ __launch_bounds__(256) void agg_kernel(
    const unsigned* __restrict__ Y, const unsigned* __restrict__ rp,
    const int* __restrict__ nbr, const unsigned* __restrict__ Z,
    const float* __restrict__ bias, unsigned* __restrict__ outb, int nrows)
{
    int wave = threadIdx.x >> 6, lane = threadIdx.x & 63;
    int r = blockIdx.x * 4 + wave;
    if (r >= nrows) return;
    unsigned beg = rp[r], end = rp[r + 1];
    float a0 = 0.f, a1 = 0.f;
    unsigned u = beg;
    for (; u + 2 <= end; u += 2) {
        int j0 = nbr[u], j1 = nbr[u + 1];
        unsigned p0 = Y[(size_t)j0 * 64 + lane];
        unsigned p1 = Y[(size_t)j1 * 64 + lane];
        a0 += bflo(p0) + bflo(p1);
        a1 += bfhi(p0) + bfhi(p1);
    }
    if (u < end) {
        unsigned p = Y[(size_t)nbr[u] * 64 + lane];
        a0 += bflo(p); a1 += bfhi(p);
    }
    unsigned c = end - beg;
    float inv = 1.f / (float)(c ? c : 1u);
    unsigned zp = Z[(size_t)r * 64 + lane];
    float2 b2 = ((const float2*)bias)[lane];
    outb[(size_t)r * 64 + lane] = packbf(fmaxf(a0 * inv + bflo(zp) + b2.x, 0.f),
                                         fmaxf(a1 * inv + bfhi(zp) + b2.y, 0.f));
}

// ---------------- fused rh aggregate (layers 2+3 share the CSR walk) ----------------
// Y23[j] = [y2 row | y3 row]; writes sotu_h = relu(m2+z2+b2); z2 <- mean3 (in place)
__global__ __launch_bounds__(256) void agg23_kernel(
    const unsigned* __restrict__ Y23, const unsigned* __restrict__ rp,
    const int* __restrict__ nbr, unsigned* __restrict__ z2m3,
    const float* __restrict__ bias2, unsigned* __restrict__ sotu_h, int nrows)
{
    int wave = threadIdx.x >> 6, lane = threadIdx.x & 63;
    int r = blockIdx.x * 4 + wave;
    if (r >= nrows) return;
    unsigned beg = rp[r], end = rp[r + 1];
    float a0 = 0.f, a1 = 0.f, a2 = 0.f, a3 = 0.f;
    unsigned u = beg;
    for (; u + 2 <= end; u += 2) {
        int j0 = nbr[u], j1 = nbr[u + 1];
        const unsigned* r0 = Y23 + (size_t)j0 * 128;
        const unsigned* r1 = Y23 + (size_t)j1 * 128;
        unsigned p0 = r0[lane], q0 = r0[64 + lane];
        unsigned p1 = r1[lane], q1 = r1[64 + lane];
        a0 += bflo(p0) + bflo(p1); a1 += bfhi(p0) + bfhi(p1);
        a2 += bflo(q0) + bflo(q1); a3 += bfhi(q0) + bfhi(q1);
    }
    if (u < end) {
        const unsigned* r0 = Y23 + (size_t)nbr[u] * 128;
        unsigned p0 = r0[lane], q0 = r0[64 + lane];
        a0 += bflo(p0); a1 += bfhi(p0); a2 += bflo(q0); a3 += bfhi(q0);
    }
    unsigned c = end - beg;
    float inv = 1.f / (float)(c ? c : 1u);
    unsigned zp = z2m3[(size_t)r * 64 + lane];
    float2 b2v = ((const float2*)bias2)[lane];
    sotu_h[(size_t)r * 64 + lane] = packbf(fmaxf(a0 * inv + bflo(zp) + b2v.x, 0.f),
                                           fmaxf(a1 * inv + bfhi(zp) + b2v.y, 0.f));
    z2m3[(size_t)r * 64 + lane] = packbf(a2 * inv, a3 * inv);
}

extern "C" void kernel_launch(void* const* d_in, const int* in_sizes, int n_in,
                              void* d_out, int out_size, void* d_ws, size_t ws_size,
                              hipStream_t stream)
{
    const float* x_taxon = (const float*)d_in[0];
    const float* x_sotu  = (const float*)d_in[1];
    const int* hp_src = (const int*)d_in[2];
    const int* hp_dst = (const int*)d_in[3];
    const int* rh_src = (const int*)d_in[4];
    const int* rh_dst = (const int*)d_in[5];
    const float* W1l = (const float*)d_in[6];
    const float* W1r = (const float*)d_in[7];
    const float* b1  = (const float*)d_in[8];
    const float* W2l = (const float*)d_in[9];
    const float* W2r = (const float*)d_in[10];
    const float* b2  = (const float*)d_in[11];
    const float* W3l = (const float*)d_in[12];
    const float* W3r = (const float*)d_in[13];
    const float* b3  = (const float*)d_in[14];
    const float* Wlin = (const float*)d_in[15];
    const float* blin = (const float*)d_in[16];
    float* out = (float*)d_out;

    // ---- workspace layout (bytes), peak ~190.7 MB ----
    char* ws = (char*)d_ws;
    unsigned* Y23      = (unsigned*)(ws);                 // [100K][128] -> h2 [200K][64]
    unsigned* h2       = Y23;
    unsigned* z2m3     = (unsigned*)(ws + 51200000);      // z2 -> mean3 in place
    unsigned* y1       = (unsigned*)(ws + 102400000);     // y1+z1 -> sotu_h
    unsigned* z1       = (unsigned*)(ws + 128000000);
    unsigned* sotu_h   = (unsigned*)(ws + 102400000);
    unsigned long long* ebuf = (unsigned long long*)(ws + 153600000);  // 16MB -> taxon_h
    unsigned* taxon_h  = (unsigned*)(ws + 153600000);     // 25.6MB (after fill2)
    int*      sorted_rh = (int*)(ws + 179200000);         // 8MB
    int*      sorted_hp = (int*)(ws + 187200000);         // 0.8MB
    unsigned* row_ptr_t = (unsigned*)(ws + 188000000);    // [100001]
    unsigned* row_ptr_s = (unsigned*)(ws + 188400064);    // [200001]
    unsigned* cnt_t     = (unsigned*)(ws + 189200128);    // [100000]
    unsigned* cnt_s     = (unsigned*)(ws + 189600128);    // [200000]
    unsigned* bcnt      = (unsigned*)(ws + 190400128);    // [NBUCK]
    unsigned* bcursor   = (unsigned*)(ws + 190400256);    // [NBUCK]
    unsigned* bsum      = (unsigned*)(ws + 190400384);    // [1024]
    unsigned short* wtbase = (unsigned short*)(ws + 190404480);
    unsigned short* Wt1l = wtbase;
    unsigned short* Wt1r = wtbase + 16384;
    unsigned short* Wt2l = wtbase + 32768;
    unsigned short* Wt2r = wtbase + 49152;
    unsigned short* Wt3l = wtbase + 65536;
    unsigned short* Wt3r = wtbase + 81920;
    unsigned short* Wtlin = wtbase + 98304;

    // zero cnt_t + cnt_s + bcnt (contiguous)
    hipMemsetAsync(cnt_t, 0, 1200128, stream);

    // ---- rh CSR (bucketed two-phase) ----
    countB_kernel<<<1024, 256, 0, stream>>>(rh_dst, bcnt, E_RH);
    scan25_kernel<<<1, 64, 0, stream>>>(bcnt, bcursor);
    partition_kernel<<<(E_RH + 2047) / 2048, 256, 0, stream>>>(rh_src, rh_dst, bcursor, ebuf, E_RH);
    count2_kernel<<<2048, 256, 0, stream>>>(ebuf, cnt_s, E_RH);
    {
        int nb = (N_SOTU + 255) / 256;    // 782
        scanA_kernel<<<nb, 256, 0, stream>>>(cnt_s, bsum, N_SOTU);
        scanB_kernel<<<1, 1024, 0, stream>>>(bsum, nb, row_ptr_s + N_SOTU);
        scanC_kernel<<<nb, 256, 0, stream>>>(cnt_s, bsum, row_ptr_s, N_SOTU);
        hipMemcpyAsync(cnt_s, row_ptr_s, (size_t)N_SOTU * 4, hipMemcpyDeviceToDevice, stream);
        fill2_kernel<<<2048, 256, 0, stream>>>(ebuf, cnt_s, sorted_rh, E_RH);
    }

    // ---- hp CSR ----
    count_hp_kernel<<<782, 256, 0, stream>>>(hp_dst, cnt_t);
    {
        int nb = (N_TAXON + 255) / 256;   // 391
        scanA_kernel<<<nb, 256, 0, stream>>>(cnt_t, bsum, N_TAXON);
        scanB_kernel<<<1, 1024, 0, stream>>>(bsum, nb, row_ptr_t + N_TAXON);
        scanC_kernel<<<nb, 256, 0, stream>>>(cnt_t, bsum, row_ptr_t, N_TAXON);
        hipMemcpyAsync(cnt_t, row_ptr_t, (size_t)N_TAXON * 4, hipMemcpyDeviceToDevice, stream);
        fill_kernel<<<782, 256, 0, stream>>>(hp_src, hp_dst, cnt_t, sorted_hp, E_HP);
    }

    // ---- weight prep ----
    wprep_kernel<<<64, 256, 0, stream>>>(W1l, Wt1l, 128);
    wprep_kernel<<<64, 256, 0, stream>>>(W1r, Wt1r, 128);
    wprep_kernel<<<64, 256, 0, stream>>>(W2l, Wt2l, 128);
    wprep_kernel<<<64, 256, 0, stream>>>(W2r, Wt2r, 128);
    wprep_kernel<<<64, 256, 0, stream>>>(W3l, Wt3l, 128);
    wprep_kernel<<<64, 256, 0, stream>>>(W3r, Wt3r, 128);
    wprep_kernel<<<32, 256, 0, stream>>>(Wlin, Wtlin, 64);

    int gT = (N_TAXON + 63) / 64, gS = (N_SOTU + 63) / 64;

    // ---- layer 1 ----
    gemm_kernel<128, true, 0><<<gT, 256, 0, stream>>>(x_taxon, Wt1l, nullptr, nullptr, y1, 64, 0, N_TAXON);
    gemm_kernel<128, true, 0><<<gT, 256, 0, stream>>>(x_taxon, Wt1r, nullptr, nullptr, z1, 64, 0, N_TAXON);
    agg_kernel<<<(N_TAXON + 3) / 4, 256, 0, stream>>>(y1, row_ptr_t, sorted_hp, z1, b1, taxon_h, N_TAXON);

    // ---- layers 2+3 GEMMs into Y23 / z2 ----
    gemm_kernel<128, true, 0><<<gT, 256, 0, stream>>>(x_taxon, Wt2l, nullptr, nullptr, Y23, 128, 0, N_TAXON);
    gemm_kernel<128, false, 0><<<gT, 256, 0, stream>>>(taxon_h, Wt3l, nullptr, nullptr, Y23, 128, 64, N_TAXON);
    gemm_kernel<128, true, 0><<<gS, 256, 0, stream>>>(x_sotu, Wt2r, nullptr, nullptr, z2m3, 64, 0, N_SOTU);

    // ---- fused rh aggregate (m2 -> sotu_h, m3 -> z2m3) ----
    agg23_kernel<<<(N_SOTU + 3) / 4, 256, 0, stream>>>(Y23, row_ptr_s, sorted_rh, z2m3, b2, sotu_h, N_SOTU);

    // ---- layer 3 GEMM with fused epilogue: h2 = relu(sotu_h @ W3r + mean3 + b3) ----
    gemm_kernel<128, false, 2><<<gS, 256, 0, stream>>>(sotu_h, Wt3r, b3, z2m3, h2, 64, 0, N_SOTU);

    // ---- final linear (f32 out, bias in init) ----
    gemm_kernel<64, false, 1><<<gS, 256, 0, stream>>>(h2, Wtlin, blin, nullptr, out, 64, 0, N_SOTU);
}

// Round 6
// 658.807 us; speedup vs baseline: 8.8276x; 1.0140x over previous
//
#include <hip/hip_runtime.h>
#include <hip/hip_bf16.h>

#define D 128
#define N_TAXON 100000
#define N_SOTU 200000
#define E_HP 200000
#define E_RH 2000000
#define OUTC 64
#define NBUCK 25      // ceil(N_SOTU / 8192)
#define BSHIFT 13

typedef __hip_bfloat16 bf16;
typedef __bf16 bf16v8 __attribute__((ext_vector_type(8)));
typedef float f32x4 __attribute__((ext_vector_type(4)));
typedef int i32x4 __attribute__((ext_vector_type(4)));
typedef unsigned u32x2 __attribute__((ext_vector_type(2)));

union Frag { i32x4 i; bf16v8 v; };

__device__ __forceinline__ float bflo(unsigned u) { return __uint_as_float(u << 16); }
__device__ __forceinline__ float bfhi(unsigned u) { return __uint_as_float(u & 0xffff0000u); }

__device__ __forceinline__ unsigned short f2bf(float x) {
    unsigned u = __float_as_uint(x);
    unsigned r = (u + 0x7fffu + ((u >> 16) & 1u)) >> 16;   // round-to-nearest-even
    return (unsigned short)r;
}
__device__ __forceinline__ unsigned packbf(float a, float b) {
    return (unsigned)f2bf(a) | ((unsigned)f2bf(b) << 16);
}

// ---------------- fused: hp per-dst degree + rh bucket histogram ----------------
__global__ __launch_bounds__(256) void countAll_kernel(const int* __restrict__ hp_dst,
                                                       const int* __restrict__ rh_dst,
                                                       unsigned* __restrict__ cnt_t,
                                                       unsigned* __restrict__ bcnt)
{
    __shared__ unsigned hist[NBUCK];
    for (int i = threadIdx.x; i < NBUCK; i += 256) hist[i] = 0;
    __syncthreads();
    int stride = gridDim.x * 256;
    for (int e = blockIdx.x * 256 + threadIdx.x; e < E_HP; e += stride)
        atomicAdd(&cnt_t[hp_dst[e]], 1u);
    for (int e = blockIdx.x * 256 + threadIdx.x; e < E_RH; e += stride)
        atomicAdd(&hist[rh_dst[e] >> BSHIFT], 1u);
    __syncthreads();
    if (threadIdx.x < NBUCK) atomicAdd(&bcnt[threadIdx.x], hist[threadIdx.x]);
}

__global__ void scan25_kernel(const unsigned* __restrict__ bcnt, unsigned* __restrict__ bcursor)
{
    if (threadIdx.x == 0) {
        unsigned acc = 0;
        for (int b = 0; b < NBUCK; ++b) { bcursor[b] = acc; acc += bcnt[b]; }
    }
}

// ---------------- rh: partition edges into dst-buckets + per-dst count ----------------
__global__ __launch_bounds__(256) void partition_kernel(
    const int* __restrict__ src, const int* __restrict__ dst,
    unsigned* __restrict__ bcursor, unsigned* __restrict__ cnt_s,
    unsigned long long* __restrict__ ebuf, int n)
{
    __shared__ unsigned hist[NBUCK];
    __shared__ unsigned lcur[NBUCK];
    int base = blockIdx.x * 2048;
    for (int i = threadIdx.x; i < NBUCK; i += 256) hist[i] = 0;
    __syncthreads();
    int s[8], d[8];
#pragma unroll
    for (int k = 0; k < 8; ++k) {
        int e = base + k * 256 + threadIdx.x;
        if (e < n) {
            s[k] = src[e]; d[k] = dst[e];
            atomicAdd(&hist[d[k] >> BSHIFT], 1u);
            atomicAdd(&cnt_s[d[k]], 1u);
        } else d[k] = -1;
    }
    __syncthreads();
    if (threadIdx.x < NBUCK)
        lcur[threadIdx.x] = atomicAdd(&bcursor[threadIdx.x], hist[threadIdx.x]);
    __syncthreads();
#pragma unroll
    for (int k = 0; k < 8; ++k) {
        if (d[k] >= 0) {
            unsigned slot = atomicAdd(&lcur[d[k] >> BSHIFT], 1u);
            ebuf[slot] = ((unsigned long long)(unsigned)d[k] << 32) | (unsigned)s[k];
        }
    }
}

// ---------------- combined 3-phase exclusive scan over [cnt_t ; cnt_s] ----------------
__global__ __launch_bounds__(256) void scanA_kernel(const unsigned* __restrict__ cnt,
                                                    unsigned* __restrict__ bsum, int n)
{
    int lane = threadIdx.x & 63, wv = threadIdx.x >> 6;
    __shared__ unsigned ws[4];
    int i = blockIdx.x * 256 + threadIdx.x;
    unsigned v = (i < n) ? cnt[i] : 0u;
    for (int off = 1; off < 64; off <<= 1) v += __shfl_xor(v, off, 64);
    if (lane == 0) ws[wv] = v;
    __syncthreads();
    if (threadIdx.x == 0) bsum[blockIdx.x] = ws[0] + ws[1] + ws[2] + ws[3];
}

// handles nb <= 2048 (2 elements per thread)
__global__ __launch_bounds__(1024) void scanB_kernel(unsigned* __restrict__ bsum, int nb,
                                                     unsigned* __restrict__ total_out)
{
    int lane = threadIdx.x & 63, wv = threadIdx.x >> 6;
    __shared__ unsigned wsum[16];
    int t = threadIdx.x;
    unsigned v0 = (2 * t     < nb) ? bsum[2 * t]     : 0u;
    unsigned v1 = (2 * t + 1 < nb) ? bsum[2 * t + 1] : 0u;
    unsigned v = v0 + v1;
    unsigned s = v;
    for (int off = 1; off < 64; off <<= 1) {
        unsigned tt = __shfl_up(s, off, 64);
        if (lane >= off) s += tt;
    }
    if (lane == 63) wsum[wv] = s;
    __syncthreads();
    unsigned woff = 0, tot = 0;
    for (int w = 0; w < 16; ++w) { if (w < wv) woff += wsum[w]; tot += wsum[w]; }
    unsigned ex = woff + s - v;
    if (2 * t     < nb) bsum[2 * t]     = ex;
    if (2 * t + 1 < nb) bsum[2 * t + 1] = ex + v0;
    if (t == 0) *total_out = tot;
}

__global__ __launch_bounds__(256) void scanC_kernel(const unsigned* __restrict__ cnt,
                                                    const unsigned* __restrict__ bsum,
                                                    unsigned* __restrict__ row_ptr,
                                                    unsigned* __restrict__ cursor, int n)
{
    int lane = threadIdx.x & 63, wv = threadIdx.x >> 6;
    __shared__ unsigned wsum[4];
    int i = blockIdx.x * 256 + threadIdx.x;
    unsigned v = (i < n) ? cnt[i] : 0u;
    unsigned s = v;
    for (int off = 1; off < 64; off <<= 1) {
        unsigned t = __shfl_up(s, off, 64);
        if (lane >= off) s += t;
    }
    if (lane == 63) wsum[wv] = s;
    __syncthreads();
    unsigned woff = bsum[blockIdx.x];
    for (int w = 0; w < wv; ++w) woff += wsum[w];
    if (i < n) { unsigned p = woff + s - v; row_ptr[i] = p; cursor[i] = p; }
}

// ---------------- CSR fills into combined sorted_all ----------------
__global__ __launch_bounds__(256) void fill_hp_kernel(const int* __restrict__ src,
                                                      const int* __restrict__ dst,
                                                      unsigned* __restrict__ cursor,
                                                      int* __restrict__ sorted_all)
{
    int stride = gridDim.x * 256;
    for (int i = blockIdx.x * 256 + threadIdx.x; i < E_HP; i += stride) {
        unsigned pos = atomicAdd(&cursor[dst[i]], 1u);
        sorted_all[pos] = src[i];
    }
}

__global__ __launch_bounds__(256) void fill2_kernel(const unsigned long long* __restrict__ ebuf,
                                                    unsigned* __restrict__ cursor,
                                                    int* __restrict__ sorted_all)
{
    int stride = gridDim.x * 256;
    for (int e = blockIdx.x * 256 + threadIdx.x; e < E_RH; e += stride) {
        unsigned long long v = ebuf[e];
        unsigned pos = atomicAdd(&cursor[N_TAXON + (unsigned)(v >> 32)], 1u);
        sorted_all[pos] = (int)(unsigned)v;
    }
}

// ---------------- all weights: transpose + bf16 + XOR-swizzle in one kernel ----------------
__global__ __launch_bounds__(256) void wprep_all_kernel(
    const float* __restrict__ W1l, const float* __restrict__ W1r,
    const float* __restrict__ W2l, const float* __restrict__ W2r,
    const float* __restrict__ W3l, const float* __restrict__ W3r,
    const float* __restrict__ Wlin, unsigned short* __restrict__ wtbase)
{
    int e = blockIdx.x * 256 + threadIdx.x;
    if (e >= 6 * 16384 + 8192) return;
    const float* srcs[7] = { W1l, W1r, W2l, W2r, W3l, W3r, Wlin };
    int m = e >> 14;                       // 0..5 for the 128x128s, 6 for Wlin
    int local = (m < 6) ? (e & 16383) : (e - 98304);
    int N = (m < 6) ? 128 : 64;
    int k = local / N, col = local - k * N;
    unsigned short* dst = wtbase + ((m < 6) ? m * 16384 : 98304);
    dst[(col * 128 + k) ^ ((col & 7) << 3)] = f2bf(srcs[m][local]);
}

// ---------------- MFMA GEMM: Y[M][BN] = X[M][128] @ W[128][BN] ----------------
// EPI 0: bf16-pair out (u32 stride/offset, IL = pair step)   EPI 1: f32 out + bias
// EPI 2: bf16-pair out = relu(acc + mean3 + bias)
template<int BN, bool F32A, int EPI, int IL>
__global__ __launch_bounds__(256) void gemm_kernel(
    const void* __restrict__ Xin,
    const unsigned short* __restrict__ Wt,
    const float* __restrict__ biasv,
    const unsigned* __restrict__ mean3,
    void* __restrict__ Yout, int ostride, int ooff, int M)
{
    constexpr int NCF = BN / 16;
    __shared__ char sW[BN * 256];
    for (int c = threadIdx.x; c < BN * 16; c += 256)
        ((i32x4*)sW)[c] = ((const i32x4*)Wt)[c];
    __syncthreads();

    int wave = threadIdx.x >> 6;
    int lane = threadIdx.x & 63;
    int ln = lane & 15, g = lane >> 4;
    int row = blockIdx.x * 64 + wave * 16 + ln;
    int rl = row < M ? row : M - 1;
    int swz = (ln & 7) << 4;

    f32x4 acc[NCF];
#pragma unroll
    for (int cf = 0; cf < NCF; ++cf) {
        if (EPI == 1) acc[cf] = ((const f32x4*)biasv)[cf * 4 + g];
        else for (int e = 0; e < 4; ++e) acc[cf][e] = 0.0f;
    }

#pragma unroll
    for (int ks = 0; ks < 4; ++ks) {
        Frag xf;
        if (F32A) {
            const f32x4* xr = (const f32x4*)((const float*)Xin + (size_t)rl * 128);
            f32x4 fa = xr[ks * 8 + g * 2];
            f32x4 fb = xr[ks * 8 + g * 2 + 1];
            i32x4 t = { (int)packbf(fa.x, fa.y), (int)packbf(fa.z, fa.w),
                        (int)packbf(fb.x, fb.y), (int)packbf(fb.z, fb.w) };
            xf.i = t;
        } else {
            const i32x4* xr = (const i32x4*)((const unsigned*)Xin + (size_t)rl * 64);
            xf.i = xr[ks * 4 + g];
        }
#pragma unroll
        for (int cf = 0; cf < NCF; ++cf) {
            Frag wf;
            wf.i = *(const i32x4*)(sW + ((((cf * 16 + ln) << 8) + (ks << 6) + (g << 4)) ^ swz));
            acc[cf] = __builtin_amdgcn_mfma_f32_16x16x32_bf16(wf.v, xf.v, acc[cf], 0, 0, 0);
        }
    }

    if (row < M) {
        if (EPI == 1) {
            float* orow = (float*)Yout + (size_t)row * ostride;
#pragma unroll
            for (int cf = 0; cf < NCF; ++cf)
                *(f32x4*)(orow + cf * 16 + 4 * g) = acc[cf];
        } else if (EPI == 2) {
            const unsigned* mrow = mean3 + (size_t)row * 64;
            unsigned* orow = (unsigned*)Yout + (size_t)row * ostride + ooff;
#pragma unroll
            for (int cf = 0; cf < NCF; ++cf) {
                u32x2 mp = *(const u32x2*)(mrow + cf * 8 + g * 2);
                f32x4 bv = ((const f32x4*)biasv)[cf * 4 + g];
                float o0 = fmaxf(acc[cf][0] + bflo(mp.x) + bv.x, 0.f);
                float o1 = fmaxf(acc[cf][1] + bfhi(mp.x) + bv.y, 0.f);
                float o2 = fmaxf(acc[cf][2] + bflo(mp.y) + bv.z, 0.f);
                float o3 = fmaxf(acc[cf][3] + bfhi(mp.y) + bv.w, 0.f);
                u32x2 o; o.x = packbf(o0, o1); o.y = packbf(o2, o3);
                *(u32x2*)(orow + cf * 8 + g * 2) = o;
            }
        } else {
            unsigned* orow = (unsigned*)Yout + (size_t)row * ostride + ooff;
#pragma unroll
            for (int cf = 0; cf < NCF; ++cf) {
                unsigned oa = packbf(acc[cf][0], acc[cf][1]);
                unsigned ob = packbf(acc[cf][2], acc[cf][3]);
                if (IL == 1) {
                    u32x2 o; o.x = oa; o.y = ob;
                    *(u32x2*)(orow + cf * 8 + g * 2) = o;
                } else {
                    int p = cf * 8 + g * 2;
                    orow[p * IL] = oa;
                    orow[(p + 1) * IL] = ob;
                }
            }
        }
    }
}

// ---------------- fused dual GEMM: y1 = X@WtA, z1 = X@WtB (X f32), one X pass ----------------
__global__ __launch_bounds__(256) void gemm2_kernel(
    const float* __restrict__ X,
    const unsigned short* __restrict__ WtA, const unsigned short* __restrict__ WtB,
    unsigned* __restrict__ Ya, unsigned* __restrict__ Yb, int M)
{
    __shared__ char sW[65536];
    for (int c = threadIdx.x; c < 4096; c += 256)
        ((i32x4*)sW)[c] = (c < 2048) ? ((const i32x4*)WtA)[c] : ((const i32x4*)WtB)[c - 2048];
    __syncthreads();

    int wave = threadIdx.x >> 6;
    int lane = threadIdx.x & 63;
    int ln = lane & 15, g = lane >> 4;
    int row = blockIdx.x * 64 + wave * 16 + ln;
    int rl = row < M ? row : M - 1;
    int swz = (ln & 7) << 4;

    f32x4 accA[8], accB[8];
#pragma unroll
    for (int cf = 0; cf < 8; ++cf)
        for (int e = 0; e < 4; ++e) { accA[cf][e] = 0.f; accB[cf][e] = 0.f; }

    const f32x4* xr = (const f32x4*)(X + (size_t)rl * 128);
#pragma unroll
    for (int ks = 0; ks < 4; ++ks) {
        f32x4 fa = xr[ks * 8 + g * 2];
        f32x4 fb = xr[ks * 8 + g * 2 + 1];
        Frag xf;
        i32x4 t = { (int)packbf(fa.x, fa.y), (int)packbf(fa.z, fa.w),
                    (int)packbf(fb.x, fb.y), (int)packbf(fb.z, fb.w) };
        xf.i = t;
#pragma unroll
        for (int cf = 0; cf < 8; ++cf) {
            int off = (((cf * 16 + ln) << 8) + (ks << 6) + (g << 4)) ^ swz;
            Frag wa; wa.i = *(const i32x4*)(sW + off);
            Frag wb; wb.i = *(const i32x4*)(sW + 32768 + off);
            accA[cf] = __builtin_amdgcn_mfma_f32_16x16x32_bf16(wa.v, xf.v, accA[cf], 0, 0, 0);
            accB[cf] = __builtin_amdgcn_mfma_f32_16x16x32_bf16(wb.v, xf.v, accB[cf], 0, 0, 0);
        }
    }

    if (row < M) {
        unsigned* ra = Ya + (size_t)row * 64;
        unsigned* rb = Yb + (size_t)row * 64;
#pragma unroll
        for (int cf = 0; cf < 8; ++cf) {
            u32x2 oa, ob;
            oa.x = packbf(accA[cf][0], accA[cf][1]); oa.y = packbf(accA[cf][2], accA[cf][3]);
            ob.x = packbf(accB[cf][0], accB[cf][1]); ob.y = packbf(accB[cf][2], accB[cf][3]);
            *(u32x2*)(ra + cf * 8 + g * 2) = oa;
            *(u32x2*)(rb + cf * 8 + g * 2) = ob;
        }
    }
}

// ---------------- layer-1 aggregate: out = relu(mean_nbr(Y) + Z + bias) ----------------
__global__ __launch_bounds__(256) void agg_kernel(
    const unsigned* __restrict__ Y, const unsigned* __restrict__ rp,
    const int* __restrict__ nbr, const unsigned* __restrict__ Z,
    const float* __restrict__ bias, unsigned* __restrict__ outb, int nrows)
{
    int wave = threadIdx.x >> 6, lane = threadIdx.x & 63;
    int r = blockIdx.x * 4 + wave;
    if (r >= nrows) return;
    unsigned beg = rp[r], end = rp[r + 1];
    float a0 = 0.f, a1 = 0.f;
    unsigned u = beg;
    for (; u + 2 <= end; u += 2) {
        int j0 = nbr[u], j1 = nbr[u + 1];
        unsigned p0 = Y[(size_t)j0 * 64 + lane];
        unsigned p1 = Y[(size_t)j1 * 64 + lane];
        a0 += bflo(p0) + bflo(p1);
        a1 += bfhi(p0) + bfhi(p1);
    }
    if (u < end) {
        unsigned p = Y[(size_t)nbr[u] * 64 + lane];
        a0 += bflo(p); a1 += bfhi(p);
    }
    unsigned c = end - beg;
    float inv = 1.f / (float)(c ? c : 1u);
    unsigned zp = Z[(size_t)r * 64 + lane];
    float2 b2 = ((const float2*)bias)[lane];
    outb[(size_t)r * 64 + lane] = packbf(fmaxf(a0 * inv + bflo(zp) + b2.x, 0.f),
                                         fmaxf(a1 * inv + bfhi(zp) + b2.y, 0.f));
}

// ---------------- fused rh aggregate (layers 2+3, interleaved Y23, dwordx2) ----------------
__global__ __launch_bounds__(256) void agg23_kernel(
    const unsigned* __restrict__ Y23, const unsigned* __restrict__ rp,
    const int* __restrict__ nbr, unsigned* __restrict__ z2m3,
    const float* __restrict__ bias2, unsigned* __restrict__ sotu_h, int nrows)
{
    int wave = threadIdx.x >> 6, lane = threadIdx.x & 63;
    int r = blockIdx.x * 4 + wave;
    if (r >= nrows) return;
    unsigned beg = rp[r], end = rp[r + 1];
    float a0 = 0.f, a1 = 0.f, a2 = 0.f, a3 = 0.f;
    unsigned u = beg;
    for (; u + 2 <= end; u += 2) {
        int j0 = nbr[u], j1 = nbr[u + 1];
        u32x2 A = *(const u32x2*)(Y23 + (size_t)j0 * 128 + lane * 2);
        u32x2 B = *(const u32x2*)(Y23 + (size_t)j1 * 128 + lane * 2);
        a0 += bflo(A.x) + bflo(B.x); a1 += bfhi(A.x) + bfhi(B.x);
        a2 += bflo(A.y) + bflo(B.y); a3 += bfhi(A.y) + bfhi(B.y);
    }
    if (u < end) {
        u32x2 A = *(const u32x2*)(Y23 + (size_t)nbr[u] * 128 + lane * 2);
        a0 += bflo(A.x); a1 += bfhi(A.x); a2 += bflo(A.y); a3 += bfhi(A.y);
    }
    unsigned c = end - beg;
    float inv = 1.f / (float)(c ? c : 1u);
    unsigned zp = z2m3[(size_t)r * 64 + lane];
    float2 b2v = ((const float2*)bias2)[lane];
    sotu_h[(size_t)r * 64 + lane] = packbf(fmaxf(a0 * inv + bflo(zp) + b2v.x, 0.f),
                                           fmaxf(a1 * inv + bfhi(zp) + b2v.y, 0.f));
    z2m3[(size_t)r * 64 + lane] = packbf(a2 * inv, a3 * inv);
}

extern "C" void kernel_launch(void* const* d_in, const int* in_sizes, int n_in,
                              void* d_out, int out_size, void* d_ws, size_t ws_size,
                              hipStream_t stream)
{
    const float* x_taxon = (const float*)d_in[0];
    const float* x_sotu  = (const float*)d_in[1];
    const int* hp_src = (const int*)d_in[2];
    const int* hp_dst = (const int*)d_in[3];
    const int* rh_src = (const int*)d_in[4];
    const int* rh_dst = (const int*)d_in[5];
    const float* W1l = (const float*)d_in[6];
    const float* W1r = (const float*)d_in[7];
    const float* b1  = (const float*)d_in[8];
    const float* W2l = (const float*)d_in[9];
    const float* W2r = (const float*)d_in[10];
    const float* b2  = (const float*)d_in[11];
    const float* W3l = (const float*)d_in[12];
    const float* W3r = (const float*)d_in[13];
    const float* b3  = (const float*)d_in[14];
    const float* Wlin = (const float*)d_in[15];
    const float* blin = (const float*)d_in[16];
    float* out = (float*)d_out;

    // ---- workspace layout (bytes), peak ~191.8 MB ----
    char* ws = (char*)d_ws;
    unsigned* Y23      = (unsigned*)(ws);                 // [100K][128] interleaved -> h2 [200K][64]
    unsigned* h2       = Y23;
    unsigned* z2m3     = (unsigned*)(ws + 51200000);      // z2 -> mean3 in place
    unsigned* y1       = (unsigned*)(ws + 102400000);     // y1+z1 -> sotu_h (51.2MB span)
    unsigned* z1       = (unsigned*)(ws + 128000000);
    unsigned* sotu_h   = (unsigned*)(ws + 102400000);
    unsigned long long* ebuf = (unsigned long long*)(ws + 153600000);  // 16MB -> taxon_h
    unsigned* taxon_h  = (unsigned*)(ws + 153600000);     // 25.6MB (after fill2)
    int*      sorted_all = (int*)(ws + 179200000);        // [E_HP + E_RH] = 8.8MB
    unsigned* row_ptr  = (unsigned*)(ws + 188000000);     // [300001]
    unsigned* cursor   = (unsigned*)(ws + 189200128);     // [300000]
    unsigned* cnt      = (unsigned*)(ws + 190400128);     // [300000]  (cnt_t ; cnt_s)
    unsigned* bcnt     = (unsigned*)(ws + 191600128);     // [32]
    unsigned* bcursor  = (unsigned*)(ws + 191600256);     // [32]
    unsigned* bsum     = (unsigned*)(ws + 191600384);     // [2048]
    unsigned short* wtbase = (unsigned short*)(ws + 191608576);  // 7 images, 212992 B
    unsigned* cnt_t = cnt;
    unsigned* cnt_s = cnt + N_TAXON;
    unsigned* row_ptr_t = row_ptr;
    unsigned* row_ptr_s = row_ptr + N_TAXON;
    unsigned short* Wt1l = wtbase;
    unsigned short* Wt1r = wtbase + 16384;
    unsigned short* Wt2l = wtbase + 32768;
    unsigned short* Wt2r = wtbase + 49152;
    unsigned short* Wt3l = wtbase + 65536;
    unsigned short* Wt3r = wtbase + 81920;
    unsigned short* Wtlin = wtbase + 98304;

    // zero cnt + bcnt (+bcursor padding)
    hipMemsetAsync(cnt, 0, 300000 * 4 + 256, stream);

    // ---- counts ----
    countAll_kernel<<<1024, 256, 0, stream>>>(hp_dst, rh_dst, cnt_t, bcnt);
    scan25_kernel<<<1, 64, 0, stream>>>(bcnt, bcursor);
    partition_kernel<<<(E_RH + 2047) / 2048, 256, 0, stream>>>(rh_src, rh_dst, bcursor, cnt_s, ebuf, E_RH);

    // ---- combined scan (300000 entries) ----
    {
        int n = N_TAXON + N_SOTU;
        int nb = (n + 255) / 256;   // 1172
        scanA_kernel<<<nb, 256, 0, stream>>>(cnt, bsum, n);
        scanB_kernel<<<1, 1024, 0, stream>>>(bsum, nb, row_ptr + n);
        scanC_kernel<<<nb, 256, 0, stream>>>(cnt, bsum, row_ptr, cursor, n);
    }

    // ---- fills ----
    fill_hp_kernel<<<782, 256, 0, stream>>>(hp_src, hp_dst, cursor, sorted_all);
    fill2_kernel<<<2048, 256, 0, stream>>>(ebuf, cursor, sorted_all);

    // ---- weight prep (all 7) ----
    wprep_all_kernel<<<(6 * 16384 + 8192 + 255) / 256, 256, 0, stream>>>(
        W1l, W1r, W2l, W2r, W3l, W3r, Wlin, wtbase);

    int gT = (N_TAXON + 63) / 64, gS = (N_SOTU + 63) / 64;

    // ---- layer 1: y1 = x@W1l, z1 = x@W1r in one x pass ----
    gemm2_kernel<<<gT, 256, 0, stream>>>(x_taxon, Wt1l, Wt1r, y1, z1, N_TAXON);
    agg_kernel<<<(N_TAXON + 3) / 4, 256, 0, stream>>>(y1, row_ptr_t, sorted_all, z1, b1, taxon_h, N_TAXON);

    // ---- layers 2+3 GEMMs into interleaved Y23 / z2 ----
    gemm_kernel<128, true, 0, 2><<<gT, 256, 0, stream>>>(x_taxon, Wt2l, nullptr, nullptr, Y23, 128, 0, N_TAXON);
    gemm_kernel<128, false, 0, 2><<<gT, 256, 0, stream>>>(taxon_h, Wt3l, nullptr, nullptr, Y23, 128, 1, N_TAXON);
    gemm_kernel<128, true, 0, 1><<<gS, 256, 0, stream>>>(x_sotu, Wt2r, nullptr, nullptr, z2m3, 64, 0, N_SOTU);

    // ---- fused rh aggregate (m2 -> sotu_h, m3 -> z2m3) ----
    agg23_kernel<<<(N_SOTU + 3) / 4, 256, 0, stream>>>(Y23, row_ptr_s, sorted_all, z2m3, b2, sotu_h, N_SOTU);

    // ---- layer 3 GEMM with fused epilogue: h2 = relu(sotu_h @ W3r + mean3 + b3) ----
    gemm_kernel<128, false, 2, 1><<<gS, 256, 0, stream>>>(sotu_h, Wt3r, b3, z2m3, h2, 64, 0, N_SOTU);

    // ---- final linear (f32 out, bias in init) ----
    gemm_kernel<64, false, 1, 1><<<gS, 256, 0, stream>>>(h2, Wtlin, blin, nullptr, out, 64, 0, N_SOTU);
}